// Round 11
// baseline (32.669 us; speedup 1.0000x reference)
//
#include <hip/hip_runtime.h>
#include <hip/hip_bf16.h>

// MultiEmbedding: out1[r,:] = sum_{l<8} W[l, x1[r,l], :]
//                 out2[r,:] = sum_{l<4} W[l, x2[r,l], :]
// W: [8, 1024, 1024] fp32, x1: [8192,8] i32, x2: [8192,4] i32.
//
// Journal: R2 naive fp32 61us. R3 bf16 table 47.7. R5 slice-packed bf16 +
// XCD-pinned slices 34.9. R6 grid.sync fusion 148us (device-scope acquire
// invalidates per-XCD L2 — never fence between warm-up and consume). R7 NT
// W-loads + manual idx pipeline 39.1 (pipeline broke compiler schedule; NT
// part never isolated). R8 16B convert stores 34.6 (neutral). R9 balanced
// gather blocks 30.6 (best). R10 normal out-stores 31.8 (REGRESSED —
// write-allocate evicts hot wb; NT out-stores are correct).
// R11: R9 exact + NT W-LOADS in convert only (isolated): the 4 MiB/XCD dead
// fp32 read stream must not evict the 2 MiB wb slice from the 4 MiB L2.
//
// Pass 1 (convert_pack): W -> bf16 packed per column-slice
//   wb[slice][l*1024+tok][128], slice = blockIdx%8 -> XCD (round-robin).
//   NT loads for W; normal stores for wb (slice stays hot in private L2).
// Pass 2 (gather): slice = blockIdx%8 (same XCD mapping) -> L2-hit reads.
//   Balanced blocks: 32 x1 rows + 32 x2 rows each. NT output stores.

#define TOKEN_DIM 1024
#define N_TOKENS  1024
#define N_LEVELS  8

#define SLICES      8
#define SLICE_COLS  128                        // TOKEN_DIM / SLICES
#define SLICE_ROWS  (N_LEVELS * N_TOKENS)      // 8192 (l,token) rows
#define SLICE_ELEMS ((size_t)SLICE_ROWS * SLICE_COLS)  // 1M bf16 = 2 MiB

#define ROWS_PER_HALF 32     // x1 rows and x2 rows per gather block
#define ROWS_PER_ITER 16     // 256 threads / 16 col-groups

typedef float          f32x4 __attribute__((ext_vector_type(4)));
typedef unsigned short u16x4 __attribute__((ext_vector_type(4)));
typedef unsigned short u16x8 __attribute__((ext_vector_type(8)));

__device__ __forceinline__ unsigned short f2bf_rne(float f) {
    unsigned int u = __float_as_uint(f);
    u += 0x7fffu + ((u >> 16) & 1u);     // round-to-nearest-even
    return (unsigned short)(u >> 16);
}
__device__ __forceinline__ float bf2f(unsigned short u) {
    return __uint_as_float(((unsigned int)u) << 16);
}

// ---- pass 1: fp32 -> bf16, packed per slice, NT reads, 16B stores ----
// blockIdx = chunk*8 + slice; 256 chunks x 32 rows = 8192 (l,tok) rows/slice.
__global__ __launch_bounds__(256) void convert_pack_kernel(
    const float* __restrict__ w, unsigned short* __restrict__ wb)
{
    const int slice  = blockIdx.x & 7;
    const int chunk  = blockIdx.x >> 3;      // 0..255
    const int lane_c = threadIdx.x & 15;     // 8 cols (16B out, 32B in)
    const int lrow   = threadIdx.x >> 4;     // 0..15
    const int row0   = chunk * 32;

    unsigned short* ws = wb + (size_t)slice * SLICE_ELEMS;

    #pragma unroll
    for (int it = 0; it < 2; ++it) {
        const int row = row0 + it * 16 + lrow;         // (l*1024 + tok)
        const float* src = w + (size_t)row * TOKEN_DIM + slice * SLICE_COLS + lane_c * 8;
        // NT loads: W is read exactly once; do NOT allocate in L2 (would
        // evict the wb lines the gather pass needs resident).
        const f32x4 va = __builtin_nontemporal_load(reinterpret_cast<const f32x4*>(src));
        const f32x4 vb = __builtin_nontemporal_load(reinterpret_cast<const f32x4*>(src) + 1);
        u16x8 o;
        o[0] = f2bf_rne(va.x); o[1] = f2bf_rne(va.y);
        o[2] = f2bf_rne(va.z); o[3] = f2bf_rne(va.w);
        o[4] = f2bf_rne(vb.x); o[5] = f2bf_rne(vb.y);
        o[6] = f2bf_rne(vb.z); o[7] = f2bf_rne(vb.w);
        *reinterpret_cast<u16x8*>(
            ws + (size_t)row * SLICE_COLS + lane_c * 8) = o;   // normal store
    }
}

// ---- pass 2: packed, column-sliced, work-balanced gather (R9 exact) ----
// blockIdx = chunk*8 + slice; chunk 0..255. Each block: 32 x1 rows then
// 32 x2 rows (384 row-gathers, uniform). Thread: g = t&15 (8 cols),
// lr = t>>4 (16 rows per iteration). NT output stores.
__global__ __launch_bounds__(256) void gather_packed_kernel(
    const int* __restrict__ x1, const int* __restrict__ x2,
    const unsigned short* __restrict__ wb, float* __restrict__ out,
    int n1, int n2)
{
    const int slice = blockIdx.x & 7;
    const int chunk = blockIdx.x >> 3;
    const int g     = threadIdx.x & 15;
    const int lr    = threadIdx.x >> 4;

    const unsigned short* ws = wb + (size_t)slice * SLICE_ELEMS;
    const int col = slice * SLICE_COLS + g * 8;
    const int row0 = chunk * ROWS_PER_HALF;

    // ---- x1 half: rows [row0, row0+32), 8 levels each ----
    #pragma unroll
    for (int it = 0; it < ROWS_PER_HALF / ROWS_PER_ITER; ++it) {
        const int row = row0 + it * ROWS_PER_ITER + lr;

        float acc[8];
        #pragma unroll
        for (int j = 0; j < 8; ++j) acc[j] = 0.f;

        const int* idx = x1 + (size_t)row * 8;
        u16x8 v[8];
        #pragma unroll
        for (int l = 0; l < 8; ++l) {
            const int tok = idx[l];
            v[l] = *reinterpret_cast<const u16x8*>(
                ws + ((size_t)l * N_TOKENS + (size_t)tok) * SLICE_COLS + g * 8);
        }
        #pragma unroll
        for (int l = 0; l < 8; ++l)
            #pragma unroll
            for (int j = 0; j < 8; ++j) acc[j] += bf2f(v[l][j]);

        f32x4 lo = { acc[0], acc[1], acc[2], acc[3] };
        f32x4 hi = { acc[4], acc[5], acc[6], acc[7] };
        float* obase = out + (size_t)row * TOKEN_DIM + col;
        __builtin_nontemporal_store(lo, reinterpret_cast<f32x4*>(obase));
        __builtin_nontemporal_store(hi, reinterpret_cast<f32x4*>(obase) + 1);
    }

    // ---- x2 half: rows [row0, row0+32), 4 levels each ----
    #pragma unroll
    for (int it = 0; it < ROWS_PER_HALF / ROWS_PER_ITER; ++it) {
        const int row = row0 + it * ROWS_PER_ITER + lr;

        float acc[8];
        #pragma unroll
        for (int j = 0; j < 8; ++j) acc[j] = 0.f;

        const int* idx = x2 + (size_t)row * 4;
        u16x8 v[4];
        #pragma unroll
        for (int l = 0; l < 4; ++l) {
            const int tok = idx[l];
            v[l] = *reinterpret_cast<const u16x8*>(
                ws + ((size_t)l * N_TOKENS + (size_t)tok) * SLICE_COLS + g * 8);
        }
        #pragma unroll
        for (int l = 0; l < 4; ++l)
            #pragma unroll
            for (int j = 0; j < 8; ++j) acc[j] += bf2f(v[l][j]);

        f32x4 lo = { acc[0], acc[1], acc[2], acc[3] };
        f32x4 hi = { acc[4], acc[5], acc[6], acc[7] };
        float* obase = out + (size_t)(n1 + row) * TOKEN_DIM + col;
        __builtin_nontemporal_store(lo, reinterpret_cast<f32x4*>(obase));
        __builtin_nontemporal_store(hi, reinterpret_cast<f32x4*>(obase) + 1);
    }
}

// ---- fallback: pure fp32 gather (if d_ws too small or odd shapes) ----
__global__ __launch_bounds__(256) void multi_embed_f32_kernel(
    const int* __restrict__ x1, const int* __restrict__ x2,
    const float* __restrict__ weight, float* __restrict__ out,
    int n1, int n2)
{
    const int row = blockIdx.x;
    const int c4  = threadIdx.x;
    f32x4 acc = (f32x4)(0.f);
    if (row < n1) {
        const int* idx = x1 + (size_t)row * 8;
        #pragma unroll
        for (int l = 0; l < 8; ++l) {
            const int tok = idx[l];
            acc += reinterpret_cast<const f32x4*>(
                weight + ((size_t)l * N_TOKENS + (size_t)tok) * TOKEN_DIM)[c4];
        }
    } else {
        const int r = row - n1;
        if (r >= n2) return;
        const int* idx = x2 + (size_t)r * 4;
        #pragma unroll
        for (int l = 0; l < 4; ++l) {
            const int tok = idx[l];
            acc += reinterpret_cast<const f32x4*>(
                weight + ((size_t)l * N_TOKENS + (size_t)tok) * TOKEN_DIM)[c4];
        }
    }
    f32x4* o = reinterpret_cast<f32x4*>(out + (size_t)row * TOKEN_DIM);
    __builtin_nontemporal_store(acc, &o[c4]);
}

extern "C" void kernel_launch(void* const* d_in, const int* in_sizes, int n_in,
                              void* d_out, int out_size, void* d_ws, size_t ws_size,
                              hipStream_t stream) {
    const int*   x1 = (const int*)d_in[0];
    const int*   x2 = (const int*)d_in[1];
    const float* w  = (const float*)d_in[2];
    float*       o  = (float*)d_out;

    const int n1 = in_sizes[0] / 8;   // 8192
    const int n2 = in_sizes[1] / 4;   // 8192

    const size_t wb_bytes = (size_t)SLICES * SLICE_ELEMS * sizeof(unsigned short);
    const bool shapes_ok = (n1 == n2) && (n1 % ROWS_PER_HALF) == 0;

    if (ws_size >= wb_bytes && shapes_ok) {
        unsigned short* wb = (unsigned short*)d_ws;
        convert_pack_kernel<<<256 * SLICES, 256, 0, stream>>>(w, wb);
        gather_packed_kernel<<<(n1 / ROWS_PER_HALF) * SLICES, 256, 0, stream>>>(
            x1, x2, wb, o, n1, n2);
    } else {
        multi_embed_f32_kernel<<<n1 + n2, 256, 0, stream>>>(x1, x2, w, o, n1, n2);
    }
}

// Round 12
// 30.540 us; speedup vs baseline: 1.0697x; 1.0697x over previous
//
#include <hip/hip_runtime.h>
#include <hip/hip_bf16.h>

// MultiEmbedding: out1[r,:] = sum_{l<8} W[l, x1[r,l], :]
//                 out2[r,:] = sum_{l<4} W[l, x2[r,l], :]
// W: [8, 1024, 1024] fp32, x1: [8192,8] i32, x2: [8192,4] i32.
//
// R12 = exact R9 revert (best measured: 30.6us).
// Journal: R2 naive fp32 61us. R3 bf16 table 47.7. R5 slice-packed bf16 +
// XCD-pinned slices 34.9. R6 grid.sync fusion 148us (device-scope acquire
// invalidates per-XCD L2 — never fence between warm-up and consume). R7 NT
// W-loads + manual idx pipeline 39.1 (broke compiler schedule). R8 16B
// convert stores 34.6 (neutral). R9 balanced gather blocks 30.6 (BEST).
// R10 normal out-stores 31.8 (REGRESSED — write-allocate/RFO + evicts hot
// wb; NT out-stores correct). R11 NT W-loads isolated 32.7 (REGRESSED — NT
// read path slower for streaming; normal loads correct).
// All three memory streams' cache policies now single-variable tested;
// R9 configuration is the empirical optimum: normal W-loads, normal
// wb-stores, NT out-stores.
//
// Pass 1 (convert_pack): W -> bf16 packed per column-slice
//   wb[slice][l*1024+tok][128], slice = blockIdx%8 -> XCD (round-robin).
//   Each XCD's 2 MiB slice stays hot in its private 4 MiB L2.
// Pass 2 (gather): slice = blockIdx%8 (same XCD mapping) -> L2-hit reads.
//   Balanced blocks: 32 x1 rows + 32 x2 rows each (384 row-gathers,
//   uniform duration, flat tail). NT output stores.

#define TOKEN_DIM 1024
#define N_TOKENS  1024
#define N_LEVELS  8

#define SLICES      8
#define SLICE_COLS  128                        // TOKEN_DIM / SLICES
#define SLICE_ROWS  (N_LEVELS * N_TOKENS)      // 8192 (l,token) rows
#define SLICE_ELEMS ((size_t)SLICE_ROWS * SLICE_COLS)  // 1M bf16 = 2 MiB

#define ROWS_PER_HALF 32     // x1 rows and x2 rows per gather block
#define ROWS_PER_ITER 16     // 256 threads / 16 col-groups

typedef float          f32x4 __attribute__((ext_vector_type(4)));
typedef unsigned short u16x4 __attribute__((ext_vector_type(4)));
typedef unsigned short u16x8 __attribute__((ext_vector_type(8)));

__device__ __forceinline__ unsigned short f2bf_rne(float f) {
    unsigned int u = __float_as_uint(f);
    u += 0x7fffu + ((u >> 16) & 1u);     // round-to-nearest-even
    return (unsigned short)(u >> 16);
}
__device__ __forceinline__ float bf2f(unsigned short u) {
    return __uint_as_float(((unsigned int)u) << 16);
}

// ---- pass 1: fp32 -> bf16, packed per slice, L2-warm, 16B stores ----
// blockIdx = chunk*8 + slice; 256 chunks x 32 rows = 8192 (l,tok) rows/slice.
__global__ __launch_bounds__(256) void convert_pack_kernel(
    const float* __restrict__ w, unsigned short* __restrict__ wb)
{
    const int slice  = blockIdx.x & 7;
    const int chunk  = blockIdx.x >> 3;      // 0..255
    const int lane_c = threadIdx.x & 15;     // 8 cols (16B out, 32B in)
    const int lrow   = threadIdx.x >> 4;     // 0..15
    const int row0   = chunk * 32;

    unsigned short* ws = wb + (size_t)slice * SLICE_ELEMS;

    #pragma unroll
    for (int it = 0; it < 2; ++it) {
        const int row = row0 + it * 16 + lrow;         // (l*1024 + tok)
        const float* src = w + (size_t)row * TOKEN_DIM + slice * SLICE_COLS + lane_c * 8;
        const f32x4 va = *reinterpret_cast<const f32x4*>(src);
        const f32x4 vb = *reinterpret_cast<const f32x4*>(src + 4);
        u16x8 o;
        o[0] = f2bf_rne(va.x); o[1] = f2bf_rne(va.y);
        o[2] = f2bf_rne(va.z); o[3] = f2bf_rne(va.w);
        o[4] = f2bf_rne(vb.x); o[5] = f2bf_rne(vb.y);
        o[6] = f2bf_rne(vb.z); o[7] = f2bf_rne(vb.w);
        *reinterpret_cast<u16x8*>(
            ws + (size_t)row * SLICE_COLS + lane_c * 8) = o;   // normal store
    }
}

// ---- pass 2: packed, column-sliced, work-balanced gather ----
// blockIdx = chunk*8 + slice; chunk 0..255. Each block: 32 x1 rows then
// 32 x2 rows (384 row-gathers, uniform). Thread: g = t&15 (8 cols),
// lr = t>>4 (16 rows per iteration). NT output stores.
__global__ __launch_bounds__(256) void gather_packed_kernel(
    const int* __restrict__ x1, const int* __restrict__ x2,
    const unsigned short* __restrict__ wb, float* __restrict__ out,
    int n1, int n2)
{
    const int slice = blockIdx.x & 7;
    const int chunk = blockIdx.x >> 3;
    const int g     = threadIdx.x & 15;
    const int lr    = threadIdx.x >> 4;

    const unsigned short* ws = wb + (size_t)slice * SLICE_ELEMS;
    const int col = slice * SLICE_COLS + g * 8;
    const int row0 = chunk * ROWS_PER_HALF;

    // ---- x1 half: rows [row0, row0+32), 8 levels each ----
    #pragma unroll
    for (int it = 0; it < ROWS_PER_HALF / ROWS_PER_ITER; ++it) {
        const int row = row0 + it * ROWS_PER_ITER + lr;

        float acc[8];
        #pragma unroll
        for (int j = 0; j < 8; ++j) acc[j] = 0.f;

        const int* idx = x1 + (size_t)row * 8;
        u16x8 v[8];
        #pragma unroll
        for (int l = 0; l < 8; ++l) {
            const int tok = idx[l];
            v[l] = *reinterpret_cast<const u16x8*>(
                ws + ((size_t)l * N_TOKENS + (size_t)tok) * SLICE_COLS + g * 8);
        }
        #pragma unroll
        for (int l = 0; l < 8; ++l)
            #pragma unroll
            for (int j = 0; j < 8; ++j) acc[j] += bf2f(v[l][j]);

        f32x4 lo = { acc[0], acc[1], acc[2], acc[3] };
        f32x4 hi = { acc[4], acc[5], acc[6], acc[7] };
        float* obase = out + (size_t)row * TOKEN_DIM + col;
        __builtin_nontemporal_store(lo, reinterpret_cast<f32x4*>(obase));
        __builtin_nontemporal_store(hi, reinterpret_cast<f32x4*>(obase) + 1);
    }

    // ---- x2 half: rows [row0, row0+32), 4 levels each ----
    #pragma unroll
    for (int it = 0; it < ROWS_PER_HALF / ROWS_PER_ITER; ++it) {
        const int row = row0 + it * ROWS_PER_ITER + lr;

        float acc[8];
        #pragma unroll
        for (int j = 0; j < 8; ++j) acc[j] = 0.f;

        const int* idx = x2 + (size_t)row * 4;
        u16x8 v[4];
        #pragma unroll
        for (int l = 0; l < 4; ++l) {
            const int tok = idx[l];
            v[l] = *reinterpret_cast<const u16x8*>(
                ws + ((size_t)l * N_TOKENS + (size_t)tok) * SLICE_COLS + g * 8);
        }
        #pragma unroll
        for (int l = 0; l < 4; ++l)
            #pragma unroll
            for (int j = 0; j < 8; ++j) acc[j] += bf2f(v[l][j]);

        f32x4 lo = { acc[0], acc[1], acc[2], acc[3] };
        f32x4 hi = { acc[4], acc[5], acc[6], acc[7] };
        float* obase = out + (size_t)(n1 + row) * TOKEN_DIM + col;
        __builtin_nontemporal_store(lo, reinterpret_cast<f32x4*>(obase));
        __builtin_nontemporal_store(hi, reinterpret_cast<f32x4*>(obase) + 1);
    }
}

// ---- fallback: pure fp32 gather (if d_ws too small or odd shapes) ----
__global__ __launch_bounds__(256) void multi_embed_f32_kernel(
    const int* __restrict__ x1, const int* __restrict__ x2,
    const float* __restrict__ weight, float* __restrict__ out,
    int n1, int n2)
{
    const int row = blockIdx.x;
    const int c4  = threadIdx.x;
    f32x4 acc = (f32x4)(0.f);
    if (row < n1) {
        const int* idx = x1 + (size_t)row * 8;
        #pragma unroll
        for (int l = 0; l < 8; ++l) {
            const int tok = idx[l];
            acc += reinterpret_cast<const f32x4*>(
                weight + ((size_t)l * N_TOKENS + (size_t)tok) * TOKEN_DIM)[c4];
        }
    } else {
        const int r = row - n1;
        if (r >= n2) return;
        const int* idx = x2 + (size_t)r * 4;
        #pragma unroll
        for (int l = 0; l < 4; ++l) {
            const int tok = idx[l];
            acc += reinterpret_cast<const f32x4*>(
                weight + ((size_t)l * N_TOKENS + (size_t)tok) * TOKEN_DIM)[c4];
        }
    }
    f32x4* o = reinterpret_cast<f32x4*>(out + (size_t)row * TOKEN_DIM);
    __builtin_nontemporal_store(acc, &o[c4]);
}

extern "C" void kernel_launch(void* const* d_in, const int* in_sizes, int n_in,
                              void* d_out, int out_size, void* d_ws, size_t ws_size,
                              hipStream_t stream) {
    const int*   x1 = (const int*)d_in[0];
    const int*   x2 = (const int*)d_in[1];
    const float* w  = (const float*)d_in[2];
    float*       o  = (float*)d_out;

    const int n1 = in_sizes[0] / 8;   // 8192
    const int n2 = in_sizes[1] / 4;   // 8192

    const size_t wb_bytes = (size_t)SLICES * SLICE_ELEMS * sizeof(unsigned short);
    const bool shapes_ok = (n1 == n2) && (n1 % ROWS_PER_HALF) == 0;

    if (ws_size >= wb_bytes && shapes_ok) {
        unsigned short* wb = (unsigned short*)d_ws;
        convert_pack_kernel<<<256 * SLICES, 256, 0, stream>>>(w, wb);
        gather_packed_kernel<<<(n1 / ROWS_PER_HALF) * SLICES, 256, 0, stream>>>(
            x1, x2, wb, o, n1, n2);
    } else {
        multi_embed_f32_kernel<<<n1 + n2, 256, 0, stream>>>(x1, x2, w, o, n1, n2);
    }
}